// Round 5
// baseline (2488.453 us; speedup 1.0000x reference)
//
#include <hip/hip_runtime.h>
#include <cstdint>
#include <cstddef>

#define T_LEN   4096
#define B_SZ    32
#define H_DIM   128
#define DX      128
#define K_CLS   10
#define CHUNK   32
#define NCHUNKS (T_LEN / CHUNK)
#define WMAT    (3 * H_DIM * DX)
#define XA_LD   136                // halves per x-tile row
#define XP_LD   520                // halves per xp step-row: 128*4 + 8 pad
#define HI_LD   136                // halves per hist row
#define HI_ROWS 33                 // rows 0..31 = steps, row 32 = carry-in

typedef _Float16 half2v  __attribute__((ext_vector_type(2)));
typedef _Float16 half8   __attribute__((ext_vector_type(8)));
typedef float    floatx4 __attribute__((ext_vector_type(4)));

__device__ __forceinline__ float dot2f(unsigned int w, unsigned int h, float acc) {
  return __builtin_amdgcn_fdot2(__builtin_bit_cast(half2v, w),
                                __builtin_bit_cast(half2v, h), acc, false);
}

__device__ __forceinline__ unsigned int packh2(float a, float b) {
  half2v h;
  h.x = (_Float16)a;
  h.y = (_Float16)b;
  return __builtin_bit_cast(unsigned int, h);
}

// quad reduction: after xor1+xor2 adds, all 4 lanes of the quad hold the sum.
__device__ __forceinline__ float dpp_quad_red(float x) {
  int a = __builtin_amdgcn_update_dpp(0, __builtin_bit_cast(int, x), 0xB1, 0xF, 0xF, true);
  x += __builtin_bit_cast(float, a);
  int b = __builtin_amdgcn_update_dpp(0, __builtin_bit_cast(int, x), 0x4E, 0xF, 0xF, true);
  x += __builtin_bit_cast(float, b);
  return x;
}

__device__ __forceinline__ float sigm(float x) {
  x = fminf(fmaxf(x, -30.f), 30.f);
  return __builtin_amdgcn_rcpf(1.f + __expf(-x));
}

__device__ __forceinline__ float tanhfast(float x) {
  x = fminf(fmaxf(x, -15.f), 15.f);
  float t = __expf(-2.f * x);
  return (1.f - t) * __builtin_amdgcn_rcpf(1.f + t);
}

// LDS-only barrier: waits ds ops but does NOT drain vmcnt (keeps the global
// x-prefetch in flight across scan-step barriers).
__device__ __forceinline__ void bar_lgkm() {
  asm volatile("s_waitcnt lgkmcnt(0)\n\ts_barrier" ::: "memory");
}

__global__ void __launch_bounds__(256) init_out_kernel(float* __restrict__ out,
                                                       const float* __restrict__ bfc) {
  int i = blockIdx.x * 256 + threadIdx.x;
  if (i < B_SZ * T_LEN * K_CLS) out[i] = bfc[i % K_CLS];
}

__global__ void __launch_bounds__(256) cvt_wih_kernel(const float* __restrict__ a,
                                                      const float* __restrict__ b,
                                                      _Float16* __restrict__ o) {
  int i = blockIdx.x * 256 + threadIdx.x;
  if (i < WMAT) {
    o[i]        = (_Float16)a[i];
    o[WMAT + i] = (_Float16)b[i];
  }
}

__global__ void __launch_bounds__(256, 1)
gru_scan_kernel(const float* __restrict__ x,
                const float* __restrict__ Whh_f, const float* __restrict__ bih_f,
                const float* __restrict__ bhh_f,
                const float* __restrict__ Whh_b, const float* __restrict__ bih_b,
                const float* __restrict__ bhh_b,
                const _Float16* __restrict__ w16,   // [wih_f|wih_b] f16
                const float* __restrict__ Wfc, float* __restrict__ out) {
  const int tid = threadIdx.x;
  const int bid = blockIdx.x;
  const int dir = bid >> 5;
  const int b   = bid & (B_SZ - 1);

  const float* Whh = dir ? Whh_b : Whh_f;
  const float* bih = dir ? bih_b : bih_f;
  const float* bhh = dir ? bhh_b : bhh_f;
  const _Float16* Wih16 = w16 + (size_t)dir * WMAT;

  const int lane = tid & 63;
  const int wv   = tid >> 6;     // 0..3
  const int col  = lane & 15;    // MFMA m/n index
  const int quad = lane >> 4;    // MFMA k-group

  const int q  = tid & 3;        // k-quarter (scan)
  const int j0 = (tid >> 2) * 2; // even hidden row; thread covers j0, j0+1

  __shared__ __align__(16) _Float16 xAf[CHUNK * XA_LD];
  __shared__ __align__(16) _Float16 xpL[CHUNK * XP_LD];     // [s][j*4+gate]
  __shared__ __align__(16) _Float16 histf[HI_ROWS * HI_LD]; // h history (+carry row 32)

  // ---- recurrent weights: 16 packed pairs per (j, gate) for k-quarter q ----
  unsigned int wr0[16], wz0[16], wn0[16], wr1[16], wz1[16], wn1[16];
  {
    const int j1 = j0 + 1;
    const float* r0 = Whh + (size_t)j0 * H_DIM + q * 32;
    const float* z0 = Whh + (size_t)(H_DIM + j0) * H_DIM + q * 32;
    const float* n0 = Whh + (size_t)(2 * H_DIM + j0) * H_DIM + q * 32;
    const float* r1 = Whh + (size_t)j1 * H_DIM + q * 32;
    const float* z1 = Whh + (size_t)(H_DIM + j1) * H_DIM + q * 32;
    const float* n1 = Whh + (size_t)(2 * H_DIM + j1) * H_DIM + q * 32;
#pragma unroll
    for (int i = 0; i < 16; ++i) {
      wr0[i] = packh2(r0[2 * i], r0[2 * i + 1]);
      wz0[i] = packh2(z0[2 * i], z0[2 * i + 1]);
      wn0[i] = packh2(n0[2 * i], n0[2 * i + 1]);
      wr1[i] = packh2(r1[2 * i], r1[2 * i + 1]);
      wz1[i] = packh2(z1[2 * i], z1[2 * i + 1]);
      wn1[i] = packh2(n1[2 * i], n1[2 * i + 1]);
    }
  }
  const int j1 = j0 + 1;
  const float cbr0 = bih[j0] + bhh[j0];
  const float cbz0 = bih[H_DIM + j0] + bhh[H_DIM + j0];
  const float bin0 = bih[2 * H_DIM + j0];
  const float bhn0 = bhh[2 * H_DIM + j0];
  const float cbr1 = bih[j1] + bhh[j1];
  const float cbz1 = bih[H_DIM + j1] + bhh[H_DIM + j1];
  const float bin1 = bih[2 * H_DIM + j1];
  const float bhn1 = bhh[2 * H_DIM + j1];

  // ---- Wfc fragments (stationary) ----
  half8 fcfrag[4];
#pragma unroll
  for (int ks = 0; ks < 4; ++ks) {
    half8 v;
#pragma unroll
    for (int e = 0; e < 8; ++e) {
      int cc = ks * 32 + quad * 8 + e;
      v[e] = (col < K_CLS) ? (_Float16)Wfc[(size_t)col * (2 * H_DIM) + dir * H_DIM + cc]
                           : (_Float16)0.f;
    }
    fcfrag[ks] = v;
  }

  // ---- zero carry row (h at t=0) ----
  if (tid < 64) ((unsigned int*)&histf[32 * HI_LD])[tid] = 0u;

  // ---- x prefetch ----
  const int prow  = tid >> 3;          // 0..31
  const int cbase = (tid & 7) * 16;
  float4 px0, px1, px2, px3;
  {
    int t0 = dir ? (T_LEN - 1 - prow) : prow;
    const float* xp = x + ((size_t)b * T_LEN + t0) * DX + cbase;
    px0 = *(const float4*)xp;       px1 = *(const float4*)(xp + 4);
    px2 = *(const float4*)(xp + 8); px3 = *(const float4*)(xp + 12);
  }
  __syncthreads();

  for (int ck = 0; ck < NCHUNKS; ++ck) {
    // ---- (a) stage x tile into LDS (f16) ----
    {
      half8 lo, hi;
      lo[0] = (_Float16)px0.x; lo[1] = (_Float16)px0.y; lo[2] = (_Float16)px0.z; lo[3] = (_Float16)px0.w;
      lo[4] = (_Float16)px1.x; lo[5] = (_Float16)px1.y; lo[6] = (_Float16)px1.z; lo[7] = (_Float16)px1.w;
      hi[0] = (_Float16)px2.x; hi[1] = (_Float16)px2.y; hi[2] = (_Float16)px2.z; hi[3] = (_Float16)px2.w;
      hi[4] = (_Float16)px3.x; hi[5] = (_Float16)px3.y; hi[6] = (_Float16)px3.z; hi[7] = (_Float16)px3.w;
      *(half8*)&xAf[prow * XA_LD + cbase] = lo;
      *(half8*)&xAf[prow * XA_LD + cbase + 8] = hi;
    }
    bar_lgkm();

    // ---- (b) xp = x @ Wih^T for the tile (MFMA) ----
    {
#pragma unroll
      for (int nt = 0; nt < 6; ++nt) {
        const int gg = (wv * 6 + nt) * 16 + col;
        const _Float16* wsrc = Wih16 + (size_t)gg * DX + quad * 8;
        half8 bf0 = *(const half8*)(wsrc);
        half8 bf1 = *(const half8*)(wsrc + 32);
        half8 bf2 = *(const half8*)(wsrc + 64);
        half8 bf3 = *(const half8*)(wsrc + 96);
        floatx4 a0 = (floatx4){0.f, 0.f, 0.f, 0.f};
        floatx4 a1 = (floatx4){0.f, 0.f, 0.f, 0.f};
#pragma unroll
        for (int mt = 0; mt < 2; ++mt) {
          const _Float16* ab = &xAf[(mt * 16 + col) * XA_LD + quad * 8];
          floatx4& ac = mt ? a1 : a0;
          ac = __builtin_amdgcn_mfma_f32_16x16x32_f16(*(const half8*)(ab),      bf0, ac, 0, 0, 0);
          ac = __builtin_amdgcn_mfma_f32_16x16x32_f16(*(const half8*)(ab + 32), bf1, ac, 0, 0, 0);
          ac = __builtin_amdgcn_mfma_f32_16x16x32_f16(*(const half8*)(ab + 64), bf2, ac, 0, 0, 0);
          ac = __builtin_amdgcn_mfma_f32_16x16x32_f16(*(const half8*)(ab + 96), bf3, ac, 0, 0, 0);
        }
        const int jj = (gg & 127) * 4 + (gg >> 7);
#pragma unroll
        for (int i = 0; i < 4; ++i) {
          xpL[(quad * 4 + i) * XP_LD + jj]      = (_Float16)a0[i];
          xpL[(16 + quad * 4 + i) * XP_LD + jj] = (_Float16)a1[i];
        }
      }
      if (ck + 1 < NCHUNKS) {
        int t = (ck + 1) * CHUNK + prow;
        int t0 = dir ? (T_LEN - 1 - t) : t;
        const float* xp = x + ((size_t)b * T_LEN + t0) * DX + cbase;
        px0 = *(const float4*)xp;       px1 = *(const float4*)(xp + 4);
        px2 = *(const float4*)(xp + 8); px3 = *(const float4*)(xp + 12);
      }
    }
    bar_lgkm();

    // ---- (c) scan: fdot2 with 4-way k-split, 2 j per thread ----
    int poff = 32 * HI_LD;   // previous-h row offset (carry row for s=0)
#pragma unroll 8
    for (int s = 0; s < CHUNK; ++s) {
      const uint4* hb = (const uint4*)&histf[poff + q * 32];
      uint4 H0 = hb[0], H1 = hb[1], H2 = hb[2], H3 = hb[3];
      uint4 xv = *(const uint4*)&xpL[s * XP_LD + j0 * 4];  // j0 gates + j1 gates

      unsigned int hh[16];
      hh[0]  = H0.x; hh[1]  = H0.y; hh[2]  = H0.z; hh[3]  = H0.w;
      hh[4]  = H1.x; hh[5]  = H1.y; hh[6]  = H1.z; hh[7]  = H1.w;
      hh[8]  = H2.x; hh[9]  = H2.y; hh[10] = H2.z; hh[11] = H2.w;
      hh[12] = H3.x; hh[13] = H3.y; hh[14] = H3.z; hh[15] = H3.w;

      float ar0 = 0.f, az0 = 0.f, an0 = 0.f, ar1 = 0.f, az1 = 0.f, an1 = 0.f;
#pragma unroll
      for (int i = 0; i < 16; ++i) {
        ar0 = dot2f(wr0[i], hh[i], ar0);
        az0 = dot2f(wz0[i], hh[i], az0);
        an0 = dot2f(wn0[i], hh[i], an0);
        ar1 = dot2f(wr1[i], hh[i], ar1);
        az1 = dot2f(wz1[i], hh[i], az1);
        an1 = dot2f(wn1[i], hh[i], an1);
      }
      ar0 = dpp_quad_red(ar0); az0 = dpp_quad_red(az0); an0 = dpp_quad_red(an0);
      ar1 = dpp_quad_red(ar1); az1 = dpp_quad_red(az1); an1 = dpp_quad_red(an1);

      half2v xa0 = __builtin_bit_cast(half2v, xv.x);  // xr0, xz0
      half2v xb0 = __builtin_bit_cast(half2v, xv.y);  // xn0, pad
      half2v xa1 = __builtin_bit_cast(half2v, xv.z);
      half2v xb1 = __builtin_bit_cast(half2v, xv.w);

      float rr0 = sigm((float)xa0.x + cbr0 + ar0);
      float zz0 = sigm((float)xa0.y + cbz0 + az0);
      float rr1 = sigm((float)xa1.x + cbr1 + ar1);
      float zz1 = sigm((float)xa1.y + cbz1 + az1);
      float nn0 = tanhfast((float)xb0.x + bin0 + rr0 * (an0 + bhn0));
      float nn1 = tanhfast((float)xb1.x + bin1 + rr1 * (an1 + bhn1));

      // previous h for this thread's j0,j1 (all quad lanes have it via hist read?
      // no — read own pair from hist directly: cheap b32 broadcast)
      unsigned int hprev = *(const unsigned int*)&histf[poff + j0];
      half2v hp = __builtin_bit_cast(half2v, hprev);
      float h0 = nn0 + zz0 * ((float)hp.x - nn0);
      float h1 = nn1 + zz1 * ((float)hp.y - nn1);

      if (q == 0) {
        unsigned int hw = packh2(h0, h1);
        *(unsigned int*)&histf[s * HI_LD + j0] = hw;
        if (s == CHUNK - 1) *(unsigned int*)&histf[32 * HI_LD + j0] = hw;
      }
      poff = s * HI_LD;
      bar_lgkm();
    }

    // ---- (d) fused FC over the chunk's hidden states ----
    if (wv < 2) {
      floatx4 facc = (floatx4){0.f, 0.f, 0.f, 0.f};
#pragma unroll
      for (int ks = 0; ks < 4; ++ks) {
        half8 af = *(const half8*)&histf[(wv * 16 + col) * HI_LD + ks * 32 + quad * 8];
        facc = __builtin_amdgcn_mfma_f32_16x16x32_f16(af, fcfrag[ks], facc, 0, 0, 0);
      }
      if (col < K_CLS) {
#pragma unroll
        for (int i = 0; i < 4; ++i) {
          int s  = wv * 16 + quad * 4 + i;
          int t  = ck * CHUNK + s;
          int tt = dir ? (T_LEN - 1 - t) : t;
          atomicAdd(out + ((size_t)b * T_LEN + tt) * K_CLS + col, facc[i]);
        }
      }
    }
    // FC's hist reads are fenced from next chunk's scan writes by the
    // stage+gemm barriers at the top of the next iteration.
  }
}

extern "C" void kernel_launch(void* const* d_in, const int* in_sizes, int n_in,
                              void* d_out, int out_size, void* d_ws, size_t ws_size,
                              hipStream_t stream) {
  (void)in_sizes; (void)n_in; (void)ws_size; (void)out_size;
  const float* x     = (const float*)d_in[0];
  const float* Wih_f = (const float*)d_in[1];
  const float* Whh_f = (const float*)d_in[2];
  const float* bih_f = (const float*)d_in[3];
  const float* bhh_f = (const float*)d_in[4];
  const float* Wih_b = (const float*)d_in[5];
  const float* Whh_b = (const float*)d_in[6];
  const float* bih_b = (const float*)d_in[7];
  const float* bhh_b = (const float*)d_in[8];
  const float* Wfc   = (const float*)d_in[9];
  const float* bfc   = (const float*)d_in[10];
  float* out = (float*)d_out;

  _Float16* w16 = (_Float16*)d_ws;   // [wih_f|wih_b]

  const int n_out = B_SZ * T_LEN * K_CLS;
  init_out_kernel<<<(n_out + 255) / 256, 256, 0, stream>>>(out, bfc);
  cvt_wih_kernel<<<(WMAT + 255) / 256, 256, 0, stream>>>(Wih_f, Wih_b, w16);
  gru_scan_kernel<<<B_SZ * 2, 256, 0, stream>>>(x, Whh_f, bih_f, bhh_f,
                                                Whh_b, bih_b, bhh_b,
                                                w16, Wfc, out);
}

// Round 6
// 2119.182 us; speedup vs baseline: 1.1743x; 1.1743x over previous
//
#include <hip/hip_runtime.h>
#include <cstdint>
#include <cstddef>

#define T_LEN   4096
#define B_SZ    32
#define H_DIM   128
#define DX      128
#define K_CLS   10
#define CHUNK   32
#define NCHUNKS (T_LEN / CHUNK)
#define WMAT    (3 * H_DIM * DX)
#define XA_LD   136                // halves per x-tile row
#define XP_LD   520                // halves per xp step-row: 128*4 + 8 pad
#define HI_LD   136                // halves per hist row

typedef _Float16 half2v  __attribute__((ext_vector_type(2)));
typedef _Float16 half8   __attribute__((ext_vector_type(8)));
typedef float    floatx4 __attribute__((ext_vector_type(4)));

__device__ __forceinline__ float dot2f(unsigned int w, unsigned int h, float acc) {
  return __builtin_amdgcn_fdot2(__builtin_bit_cast(half2v, w),
                                __builtin_bit_cast(half2v, h), acc, false);
}

__device__ __forceinline__ unsigned int packh2(float a, float b) {
  half2v h;
  h.x = (_Float16)a;
  h.y = (_Float16)b;
  return __builtin_bit_cast(unsigned int, h);
}

// x + x(lane^1) via DPP quad_perm(1,0,3,2); both lanes of the pair get the sum.
__device__ __forceinline__ float dpp_xor1_add(float x) {
  int xi = __builtin_bit_cast(int, x);
  int yi = __builtin_amdgcn_update_dpp(xi, xi, 0xB1, 0xF, 0xF, false);
  return x + __builtin_bit_cast(float, yi);
}

// sigmoid without clamps: exp saturates to inf/0 and rcp gives the right limit.
__device__ __forceinline__ float sigm(float x) {
  return __builtin_amdgcn_rcpf(1.f + __expf(-x));
}

// tanh with only the NaN-guard clamp on the negative side.
__device__ __forceinline__ float tanhfast(float x) {
  x = fmaxf(x, -15.f);
  float t = __expf(-2.f * x);
  return (1.f - t) * __builtin_amdgcn_rcpf(1.f + t);
}

// LDS-only barrier: waits ds ops but does NOT drain vmcnt (keeps the global
// x-prefetch in flight across scan-step barriers).
__device__ __forceinline__ void bar_lgkm() {
  asm volatile("s_waitcnt lgkmcnt(0)\n\ts_barrier" ::: "memory");
}

__global__ void __launch_bounds__(256) init_out_kernel(float* __restrict__ out,
                                                       const float* __restrict__ bfc) {
  int i = blockIdx.x * 256 + threadIdx.x;
  if (i < B_SZ * T_LEN * K_CLS) out[i] = bfc[i % K_CLS];
}

__global__ void __launch_bounds__(256) cvt_wih_kernel(const float* __restrict__ a,
                                                      const float* __restrict__ b,
                                                      _Float16* __restrict__ o) {
  int i = blockIdx.x * 256 + threadIdx.x;
  if (i < WMAT) {
    o[i]        = (_Float16)a[i];
    o[WMAT + i] = (_Float16)b[i];
  }
}

__global__ void __launch_bounds__(256, 1)
gru_scan_kernel(const float* __restrict__ x,
                const float* __restrict__ Whh_f, const float* __restrict__ bih_f,
                const float* __restrict__ bhh_f,
                const float* __restrict__ Whh_b, const float* __restrict__ bih_b,
                const float* __restrict__ bhh_b,
                const _Float16* __restrict__ w16,   // [wih_f|wih_b] f16
                const float* __restrict__ Wfc, float* __restrict__ out) {
  const int tid = threadIdx.x;
  const int bid = blockIdx.x;
  const int dir = bid >> 5;
  const int b   = bid & (B_SZ - 1);

  const float* Whh = dir ? Whh_b : Whh_f;
  const float* bih = dir ? bih_b : bih_f;
  const float* bhh = dir ? bhh_b : bhh_f;
  const _Float16* Wih16 = w16 + (size_t)dir * WMAT;

  const int lane = tid & 63;
  const int wv   = tid >> 6;     // 0..3
  const int col  = lane & 15;    // MFMA m/n index
  const int quad = lane >> 4;    // MFMA k-group

  const int j = tid >> 1;        // hidden row 0..127 (scan)
  const int q = tid & 1;         // k-half (scan)

  __shared__ __align__(16) _Float16 xAf[CHUNK * XA_LD];
  __shared__ __align__(16) _Float16 xpL[CHUNK * XP_LD];     // [s][j*4+gate]
  __shared__ __align__(16) _Float16 histf[CHUNK * HI_LD];   // unified h ring + FC input

  // ---- recurrent weights: 32 packed f16 pairs per gate (k-half q) ----
  unsigned int whr[32], whz[32], whn[32];
  {
    const float* Wr = Whh + (size_t)j * H_DIM + q * 64;
    const float* Wz = Whh + (size_t)(H_DIM + j) * H_DIM + q * 64;
    const float* Wn = Whh + (size_t)(2 * H_DIM + j) * H_DIM + q * 64;
#pragma unroll
    for (int i = 0; i < 32; ++i) {
      whr[i] = packh2(Wr[2 * i], Wr[2 * i + 1]);
      whz[i] = packh2(Wz[2 * i], Wz[2 * i + 1]);
      whn[i] = packh2(Wn[2 * i], Wn[2 * i + 1]);
    }
  }
  const float cbr  = bih[j] + bhh[j];
  const float cbz  = bih[H_DIM + j] + bhh[H_DIM + j];
  const float bin_ = bih[2 * H_DIM + j];
  const float bhn  = bhh[2 * H_DIM + j];

  // ---- Wfc fragments (stationary) ----
  half8 fcfrag[4];
#pragma unroll
  for (int ks = 0; ks < 4; ++ks) {
    half8 v;
#pragma unroll
    for (int e = 0; e < 8; ++e) {
      int cc = ks * 32 + quad * 8 + e;
      v[e] = (col < K_CLS) ? (_Float16)Wfc[(size_t)col * (2 * H_DIM) + dir * H_DIM + cc]
                           : (_Float16)0.f;
    }
    fcfrag[ks] = v;
  }

  // ---- zero row 31 (carry-in h for the first chunk's s=0) ----
  if (tid < 64) ((unsigned int*)&histf[31 * HI_LD])[tid] = 0u;

  // ---- x prefetch ----
  const int prow  = tid >> 3;          // 0..31
  const int cbase = (tid & 7) * 16;
  float4 px0, px1, px2, px3;
  {
    int t0 = dir ? (T_LEN - 1 - prow) : prow;
    const float* xp = x + ((size_t)b * T_LEN + t0) * DX + cbase;
    px0 = *(const float4*)xp;       px1 = *(const float4*)(xp + 4);
    px2 = *(const float4*)(xp + 8); px3 = *(const float4*)(xp + 12);
  }

  float hold = 0.f;    // this thread's h[j] (both q lanes track it identically)
  __syncthreads();

  for (int ck = 0; ck < NCHUNKS; ++ck) {
    // ---- (a) stage x tile into LDS (f16) ----
    {
      half8 lo, hi;
      lo[0] = (_Float16)px0.x; lo[1] = (_Float16)px0.y; lo[2] = (_Float16)px0.z; lo[3] = (_Float16)px0.w;
      lo[4] = (_Float16)px1.x; lo[5] = (_Float16)px1.y; lo[6] = (_Float16)px1.z; lo[7] = (_Float16)px1.w;
      hi[0] = (_Float16)px2.x; hi[1] = (_Float16)px2.y; hi[2] = (_Float16)px2.z; hi[3] = (_Float16)px2.w;
      hi[4] = (_Float16)px3.x; hi[5] = (_Float16)px3.y; hi[6] = (_Float16)px3.z; hi[7] = (_Float16)px3.w;
      *(half8*)&xAf[prow * XA_LD + cbase] = lo;
      *(half8*)&xAf[prow * XA_LD + cbase + 8] = hi;
    }
    bar_lgkm();

    // ---- (b) xp = x @ Wih^T for the tile (MFMA) ----
    {
#pragma unroll
      for (int nt = 0; nt < 6; ++nt) {
        const int gg = (wv * 6 + nt) * 16 + col;
        const _Float16* wsrc = Wih16 + (size_t)gg * DX + quad * 8;
        half8 bf0 = *(const half8*)(wsrc);
        half8 bf1 = *(const half8*)(wsrc + 32);
        half8 bf2 = *(const half8*)(wsrc + 64);
        half8 bf3 = *(const half8*)(wsrc + 96);
        floatx4 a0 = (floatx4){0.f, 0.f, 0.f, 0.f};
        floatx4 a1 = (floatx4){0.f, 0.f, 0.f, 0.f};
#pragma unroll
        for (int mt = 0; mt < 2; ++mt) {
          const _Float16* ab = &xAf[(mt * 16 + col) * XA_LD + quad * 8];
          floatx4& ac = mt ? a1 : a0;
          ac = __builtin_amdgcn_mfma_f32_16x16x32_f16(*(const half8*)(ab),      bf0, ac, 0, 0, 0);
          ac = __builtin_amdgcn_mfma_f32_16x16x32_f16(*(const half8*)(ab + 32), bf1, ac, 0, 0, 0);
          ac = __builtin_amdgcn_mfma_f32_16x16x32_f16(*(const half8*)(ab + 64), bf2, ac, 0, 0, 0);
          ac = __builtin_amdgcn_mfma_f32_16x16x32_f16(*(const half8*)(ab + 96), bf3, ac, 0, 0, 0);
        }
        const int jj = (gg & 127) * 4 + (gg >> 7);
#pragma unroll
        for (int i = 0; i < 4; ++i) {
          xpL[(quad * 4 + i) * XP_LD + jj]      = (_Float16)a0[i];
          xpL[(16 + quad * 4 + i) * XP_LD + jj] = (_Float16)a1[i];
        }
      }
      if (ck + 1 < NCHUNKS) {
        int t = (ck + 1) * CHUNK + prow;
        int t0 = dir ? (T_LEN - 1 - t) : t;
        const float* xp = x + ((size_t)b * T_LEN + t0) * DX + cbase;
        px0 = *(const float4*)xp;       px1 = *(const float4*)(xp + 4);
        px2 = *(const float4*)(xp + 8); px3 = *(const float4*)(xp + 12);
      }
    }
    bar_lgkm();

    // ---- (c) scan: fdot2, 2-way k-split, 1 j per thread, unified hist ring ----
#pragma unroll 8
    for (int s = 0; s < CHUNK; ++s) {
      const int pr = (s + 31) & 31;            // previous-h row (compile-time per body)
      const uint4* hb = (const uint4*)&histf[pr * HI_LD + q * 64];
      uint4 H0 = hb[0], H1 = hb[1], H2 = hb[2], H3 = hb[3];
      uint4 H4 = hb[4], H5 = hb[5], H6 = hb[6], H7 = hb[7];
      uint2 xv = *(const uint2*)&xpL[s * XP_LD + j * 4];

      unsigned int hh[32];
      hh[0]  = H0.x; hh[1]  = H0.y; hh[2]  = H0.z; hh[3]  = H0.w;
      hh[4]  = H1.x; hh[5]  = H1.y; hh[6]  = H1.z; hh[7]  = H1.w;
      hh[8]  = H2.x; hh[9]  = H2.y; hh[10] = H2.z; hh[11] = H2.w;
      hh[12] = H3.x; hh[13] = H3.y; hh[14] = H3.z; hh[15] = H3.w;
      hh[16] = H4.x; hh[17] = H4.y; hh[18] = H4.z; hh[19] = H4.w;
      hh[20] = H5.x; hh[21] = H5.y; hh[22] = H5.z; hh[23] = H5.w;
      hh[24] = H6.x; hh[25] = H6.y; hh[26] = H6.z; hh[27] = H6.w;
      hh[28] = H7.x; hh[29] = H7.y; hh[30] = H7.z; hh[31] = H7.w;

      float ar0 = 0.f, ar1 = 0.f, az0 = 0.f, az1 = 0.f, an0 = 0.f, an1 = 0.f;
#pragma unroll
      for (int i = 0; i < 16; ++i) {
        ar0 = dot2f(whr[2 * i],     hh[2 * i],     ar0);
        ar1 = dot2f(whr[2 * i + 1], hh[2 * i + 1], ar1);
        az0 = dot2f(whz[2 * i],     hh[2 * i],     az0);
        az1 = dot2f(whz[2 * i + 1], hh[2 * i + 1], az1);
        an0 = dot2f(whn[2 * i],     hh[2 * i],     an0);
        an1 = dot2f(whn[2 * i + 1], hh[2 * i + 1], an1);
      }
      float ar = dpp_xor1_add(ar0 + ar1);
      float az = dpp_xor1_add(az0 + az1);
      float an = dpp_xor1_add(an0 + an1);

      half2v x01 = __builtin_bit_cast(half2v, xv.x);
      half2v x23 = __builtin_bit_cast(half2v, xv.y);
      float rr = sigm((float)x01.x + cbr + ar);
      float zz = sigm((float)x01.y + cbz + az);
      float nn = tanhfast((float)x23.x + bin_ + rr * (an + bhn));
      hold = nn + zz * (hold - nn);

      if (q == 0) histf[s * HI_LD + j] = (_Float16)hold;
      bar_lgkm();
    }

    // ---- (d) fused FC over the chunk's hidden states ----
    if (wv < 2) {
      floatx4 facc = (floatx4){0.f, 0.f, 0.f, 0.f};
#pragma unroll
      for (int ks = 0; ks < 4; ++ks) {
        half8 af = *(const half8*)&histf[(wv * 16 + col) * HI_LD + ks * 32 + quad * 8];
        facc = __builtin_amdgcn_mfma_f32_16x16x32_f16(af, fcfrag[ks], facc, 0, 0, 0);
      }
      if (col < K_CLS) {
#pragma unroll
        for (int i = 0; i < 4; ++i) {
          int s  = wv * 16 + quad * 4 + i;
          int t  = ck * CHUNK + s;
          int tt = dir ? (T_LEN - 1 - t) : t;
          atomicAdd(out + ((size_t)b * T_LEN + tt) * K_CLS + col, facc[i]);
        }
      }
    }
    // FC's hist reads are fenced from next chunk's scan writes by the two
    // barriers in (a)/(b); row 31 doubles as the cross-chunk carry.
  }
}

extern "C" void kernel_launch(void* const* d_in, const int* in_sizes, int n_in,
                              void* d_out, int out_size, void* d_ws, size_t ws_size,
                              hipStream_t stream) {
  (void)in_sizes; (void)n_in; (void)ws_size; (void)out_size;
  const float* x     = (const float*)d_in[0];
  const float* Wih_f = (const float*)d_in[1];
  const float* Whh_f = (const float*)d_in[2];
  const float* bih_f = (const float*)d_in[3];
  const float* bhh_f = (const float*)d_in[4];
  const float* Wih_b = (const float*)d_in[5];
  const float* Whh_b = (const float*)d_in[6];
  const float* bih_b = (const float*)d_in[7];
  const float* bhh_b = (const float*)d_in[8];
  const float* Wfc   = (const float*)d_in[9];
  const float* bfc   = (const float*)d_in[10];
  float* out = (float*)d_out;

  _Float16* w16 = (_Float16*)d_ws;   // [wih_f|wih_b]

  const int n_out = B_SZ * T_LEN * K_CLS;
  init_out_kernel<<<(n_out + 255) / 256, 256, 0, stream>>>(out, bfc);
  cvt_wih_kernel<<<(WMAT + 255) / 256, 256, 0, stream>>>(Wih_f, Wih_b, w16);
  gru_scan_kernel<<<B_SZ * 2, 256, 0, stream>>>(x, Whh_f, bih_f, bhh_f,
                                                Whh_b, bih_b, bhh_b,
                                                w16, Wfc, out);
}

// Round 7
// 2081.503 us; speedup vs baseline: 1.1955x; 1.0181x over previous
//
#include <hip/hip_runtime.h>
#include <cstdint>
#include <cstddef>

#define T_LEN   4096
#define B_SZ    32
#define H_DIM   128
#define DX      128
#define K_CLS   10
#define CHUNK   32
#define NCHUNKS (T_LEN / CHUNK)
#define WMAT    (3 * H_DIM * DX)
#define XA_LD   136                // halves per x-tile row
#define XP_LD   520                // halves per xp step-row: 128*4 + 8 pad
#define HI_LD   136                // halves per hist row (272 B, 16B-aligned)

typedef _Float16 half2v  __attribute__((ext_vector_type(2)));
typedef _Float16 half8   __attribute__((ext_vector_type(8)));
typedef float    floatx4 __attribute__((ext_vector_type(4)));

__device__ __forceinline__ float dot2f(unsigned int w, unsigned int h, float acc) {
  return __builtin_amdgcn_fdot2(__builtin_bit_cast(half2v, w),
                                __builtin_bit_cast(half2v, h), acc, false);
}

__device__ __forceinline__ unsigned int packh2(float a, float b) {
  half2v h;
  h.x = (_Float16)a;
  h.y = (_Float16)b;
  return __builtin_bit_cast(unsigned int, h);
}

// row_ror:N within rows of 16 — dst[i] = src[(i-N)&15] (AMD row_shr convention).
template <int N>
__device__ __forceinline__ unsigned int ror16(unsigned int v) {
  return (unsigned int)__builtin_amdgcn_update_dpp((int)v, (int)v, 0x120 + N, 0xF, 0xF, false);
}

template <int N>
__device__ __forceinline__ uint4 ror16x4(uint4 v) {
  uint4 r;
  r.x = ror16<N>(v.x);
  r.y = ror16<N>(v.y);
  r.z = ror16<N>(v.z);
  r.w = ror16<N>(v.w);
  return r;
}

// x + x(lane^1) via DPP quad_perm(1,0,3,2); both lanes of the pair get the sum.
__device__ __forceinline__ float dpp_xor1_add(float x) {
  int xi = __builtin_bit_cast(int, x);
  int yi = __builtin_amdgcn_update_dpp(xi, xi, 0xB1, 0xF, 0xF, false);
  return x + __builtin_bit_cast(float, yi);
}

__device__ __forceinline__ float sigm(float x) {
  return __builtin_amdgcn_rcpf(1.f + __expf(-x));
}

__device__ __forceinline__ float tanhfast(float x) {
  x = fmaxf(x, -15.f);
  float t = __expf(-2.f * x);
  return (1.f - t) * __builtin_amdgcn_rcpf(1.f + t);
}

__global__ void __launch_bounds__(256) init_out_kernel(float* __restrict__ out,
                                                       const float* __restrict__ bfc) {
  int i = blockIdx.x * 256 + threadIdx.x;
  if (i < B_SZ * T_LEN * K_CLS) out[i] = bfc[i % K_CLS];
}

__global__ void __launch_bounds__(256) cvt_wih_kernel(const float* __restrict__ a,
                                                      const float* __restrict__ b,
                                                      _Float16* __restrict__ o) {
  int i = blockIdx.x * 256 + threadIdx.x;
  if (i < WMAT) {
    o[i]        = (_Float16)a[i];
    o[WMAT + i] = (_Float16)b[i];
  }
}

__global__ void __launch_bounds__(256, 1)
gru_scan_kernel(const float* __restrict__ x,
                const float* __restrict__ Whh_f, const float* __restrict__ bih_f,
                const float* __restrict__ bhh_f,
                const float* __restrict__ Whh_b, const float* __restrict__ bih_b,
                const float* __restrict__ bhh_b,
                const _Float16* __restrict__ w16,   // [wih_f|wih_b] f16
                const float* __restrict__ Wfc, float* __restrict__ out) {
  const int tid = threadIdx.x;
  const int bid = blockIdx.x;
  const int dir = bid >> 5;
  const int b   = bid & (B_SZ - 1);

  const float* Whh = dir ? Whh_b : Whh_f;
  const float* bih = dir ? bih_b : bih_f;
  const float* bhh = dir ? bhh_b : bhh_f;
  const _Float16* Wih16 = w16 + (size_t)dir * WMAT;

  const int lane = tid & 63;
  const int wv   = tid >> 6;     // 0..3
  const int col  = lane & 15;    // MFMA m/n index
  const int quad = lane >> 4;    // MFMA k-group

  const int j = tid >> 1;        // hidden row 0..127 (scan)
  const int q = tid & 1;         // k-half (scan)
  const int k8 = (lane >> 1) & 7;          // this lane's base chunk within its k-half
  const int cch = k8 + q * 8;              // chunk index 0..15 in the 256B h-row

  __shared__ __align__(16) _Float16 xAf[CHUNK * XA_LD];
  __shared__ __align__(16) _Float16 xpL[CHUNK * XP_LD];     // [s][j*4+gate]
  __shared__ __align__(16) _Float16 histf[CHUNK * HI_LD];   // unified h ring + FC input

  // ---- recurrent weights, rotation-matched layout ----
  // slot i (i=0..7) multiplies the chunk received by row_ror:(2i):
  //   chunk ((k8 - i) & 7) of this lane's k-half -> columns q*64 + ((k8-i)&7)*8 ..+8
  unsigned int whr[32], whz[32], whn[32];
  {
    const float* Wr = Whh + (size_t)j * H_DIM;
    const float* Wz = Whh + (size_t)(H_DIM + j) * H_DIM;
    const float* Wn = Whh + (size_t)(2 * H_DIM + j) * H_DIM;
#pragma unroll
    for (int i = 0; i < 8; ++i) {
      const int cb = q * 64 + (((k8 - i) & 7) * 8);
#pragma unroll
      for (int m = 0; m < 4; ++m) {
        whr[i * 4 + m] = packh2(Wr[cb + 2 * m], Wr[cb + 2 * m + 1]);
        whz[i * 4 + m] = packh2(Wz[cb + 2 * m], Wz[cb + 2 * m + 1]);
        whn[i * 4 + m] = packh2(Wn[cb + 2 * m], Wn[cb + 2 * m + 1]);
      }
    }
  }
  const float cbr  = bih[j] + bhh[j];
  const float cbz  = bih[H_DIM + j] + bhh[H_DIM + j];
  const float bin_ = bih[2 * H_DIM + j];
  const float bhn  = bhh[2 * H_DIM + j];

  // ---- Wfc fragments (stationary) ----
  half8 fcfrag[4];
#pragma unroll
  for (int ks = 0; ks < 4; ++ks) {
    half8 v;
#pragma unroll
    for (int e = 0; e < 8; ++e) {
      int cc = ks * 32 + quad * 8 + e;
      v[e] = (col < K_CLS) ? (_Float16)Wfc[(size_t)col * (2 * H_DIM) + dir * H_DIM + cc]
                           : (_Float16)0.f;
    }
    fcfrag[ks] = v;
  }

  // ---- zero row 31 (carry-in h for the first chunk's s=0) ----
  if (tid < 64) ((unsigned int*)&histf[31 * HI_LD])[tid] = 0u;

  // ---- x prefetch ----
  const int prow  = tid >> 3;          // 0..31
  const int cbase = (tid & 7) * 16;
  float4 px0, px1, px2, px3;
  {
    int t0 = dir ? (T_LEN - 1 - prow) : prow;
    const float* xp = x + ((size_t)b * T_LEN + t0) * DX + cbase;
    px0 = *(const float4*)xp;       px1 = *(const float4*)(xp + 4);
    px2 = *(const float4*)(xp + 8); px3 = *(const float4*)(xp + 12);
  }

  float hold = 0.f;    // this thread's h[j]
  __syncthreads();

  for (int ck = 0; ck < NCHUNKS; ++ck) {
    // ---- (a) stage x tile into LDS (f16) ----
    {
      half8 lo, hi;
      lo[0] = (_Float16)px0.x; lo[1] = (_Float16)px0.y; lo[2] = (_Float16)px0.z; lo[3] = (_Float16)px0.w;
      lo[4] = (_Float16)px1.x; lo[5] = (_Float16)px1.y; lo[6] = (_Float16)px1.z; lo[7] = (_Float16)px1.w;
      hi[0] = (_Float16)px2.x; hi[1] = (_Float16)px2.y; hi[2] = (_Float16)px2.z; hi[3] = (_Float16)px2.w;
      hi[4] = (_Float16)px3.x; hi[5] = (_Float16)px3.y; hi[6] = (_Float16)px3.z; hi[7] = (_Float16)px3.w;
      *(half8*)&xAf[prow * XA_LD + cbase] = lo;
      *(half8*)&xAf[prow * XA_LD + cbase + 8] = hi;
    }
    __syncthreads();

    // ---- (b) xp = x @ Wih^T for the tile (MFMA) ----
    {
#pragma unroll
      for (int nt = 0; nt < 6; ++nt) {
        const int gg = (wv * 6 + nt) * 16 + col;
        const _Float16* wsrc = Wih16 + (size_t)gg * DX + quad * 8;
        half8 bf0 = *(const half8*)(wsrc);
        half8 bf1 = *(const half8*)(wsrc + 32);
        half8 bf2 = *(const half8*)(wsrc + 64);
        half8 bf3 = *(const half8*)(wsrc + 96);
        floatx4 a0 = (floatx4){0.f, 0.f, 0.f, 0.f};
        floatx4 a1 = (floatx4){0.f, 0.f, 0.f, 0.f};
#pragma unroll
        for (int mt = 0; mt < 2; ++mt) {
          const _Float16* ab = &xAf[(mt * 16 + col) * XA_LD + quad * 8];
          floatx4& ac = mt ? a1 : a0;
          ac = __builtin_amdgcn_mfma_f32_16x16x32_f16(*(const half8*)(ab),      bf0, ac, 0, 0, 0);
          ac = __builtin_amdgcn_mfma_f32_16x16x32_f16(*(const half8*)(ab + 32), bf1, ac, 0, 0, 0);
          ac = __builtin_amdgcn_mfma_f32_16x16x32_f16(*(const half8*)(ab + 64), bf2, ac, 0, 0, 0);
          ac = __builtin_amdgcn_mfma_f32_16x16x32_f16(*(const half8*)(ab + 96), bf3, ac, 0, 0, 0);
        }
        const int jj = (gg & 127) * 4 + (gg >> 7);
#pragma unroll
        for (int i = 0; i < 4; ++i) {
          xpL[(quad * 4 + i) * XP_LD + jj]      = (_Float16)a0[i];
          xpL[(16 + quad * 4 + i) * XP_LD + jj] = (_Float16)a1[i];
        }
      }
      if (ck + 1 < NCHUNKS) {
        int t = (ck + 1) * CHUNK + prow;
        int t0 = dir ? (T_LEN - 1 - t) : t;
        const float* xp = x + ((size_t)b * T_LEN + t0) * DX + cbase;
        px0 = *(const float4*)xp;       px1 = *(const float4*)(xp + 4);
        px2 = *(const float4*)(xp + 8); px3 = *(const float4*)(xp + 12);
      }
    }
    __syncthreads();

    // ---- (c) scan: distributed h-read + DPP redistribution ----
#pragma unroll 1
    for (int g = 0; g < 4; ++g) {
      // pre-load this group's xp gate-triples into registers (off the step path)
      uint2 xg[8];
#pragma unroll
      for (int u = 0; u < 8; ++u)
        xg[u] = *(const uint2*)&xpL[(g * 8 + u) * XP_LD + j * 4];

#pragma unroll
      for (int u = 0; u < 8; ++u) {
        const int s  = g * 8 + u;
        const int pr = (s + 31) & 31;
        // one distributed b128: this lane's chunk cch of the previous h-row
        uint4 h0 = *(const uint4*)&histf[pr * HI_LD + cch * 8];
        // redistribute: slot i = chunk ((k8 - i) & 7) of this k-half
        uint4 hr1 = ror16<2>(h0.x)  ? (uint4){0,0,0,0} : (uint4){0,0,0,0}; // placeholder removed below
        (void)hr1;
        uint4 hs[8];
        hs[0] = h0;
        hs[1] = ror16x4<2>(h0);
        hs[2] = ror16x4<4>(h0);
        hs[3] = ror16x4<6>(h0);
        hs[4] = ror16x4<8>(h0);
        hs[5] = ror16x4<10>(h0);
        hs[6] = ror16x4<12>(h0);
        hs[7] = ror16x4<14>(h0);

        float ar0 = 0.f, ar1 = 0.f, az0 = 0.f, az1 = 0.f, an0 = 0.f, an1 = 0.f;
#pragma unroll
        for (int i = 0; i < 8; i += 2) {
          ar0 = dot2f(whr[i * 4 + 0], hs[i].x, ar0);
          ar0 = dot2f(whr[i * 4 + 1], hs[i].y, ar0);
          ar0 = dot2f(whr[i * 4 + 2], hs[i].z, ar0);
          ar0 = dot2f(whr[i * 4 + 3], hs[i].w, ar0);
          ar1 = dot2f(whr[i * 4 + 4], hs[i + 1].x, ar1);
          ar1 = dot2f(whr[i * 4 + 5], hs[i + 1].y, ar1);
          ar1 = dot2f(whr[i * 4 + 6], hs[i + 1].z, ar1);
          ar1 = dot2f(whr[i * 4 + 7], hs[i + 1].w, ar1);
          az0 = dot2f(whz[i * 4 + 0], hs[i].x, az0);
          az0 = dot2f(whz[i * 4 + 1], hs[i].y, az0);
          az0 = dot2f(whz[i * 4 + 2], hs[i].z, az0);
          az0 = dot2f(whz[i * 4 + 3], hs[i].w, az0);
          az1 = dot2f(whz[i * 4 + 4], hs[i + 1].x, az1);
          az1 = dot2f(whz[i * 4 + 5], hs[i + 1].y, az1);
          az1 = dot2f(whz[i * 4 + 6], hs[i + 1].z, az1);
          az1 = dot2f(whz[i * 4 + 7], hs[i + 1].w, az1);
          an0 = dot2f(whn[i * 4 + 0], hs[i].x, an0);
          an0 = dot2f(whn[i * 4 + 1], hs[i].y, an0);
          an0 = dot2f(whn[i * 4 + 2], hs[i].z, an0);
          an0 = dot2f(whn[i * 4 + 3], hs[i].w, an0);
          an1 = dot2f(whn[i * 4 + 4], hs[i + 1].x, an1);
          an1 = dot2f(whn[i * 4 + 5], hs[i + 1].y, an1);
          an1 = dot2f(whn[i * 4 + 6], hs[i + 1].z, an1);
          an1 = dot2f(whn[i * 4 + 7], hs[i + 1].w, an1);
        }
        float ar = dpp_xor1_add(ar0 + ar1);
        float az = dpp_xor1_add(az0 + az1);
        float an = dpp_xor1_add(an0 + an1);

        half2v x01 = __builtin_bit_cast(half2v, xg[u].x);
        half2v x23 = __builtin_bit_cast(half2v, xg[u].y);
        float rr = sigm((float)x01.x + cbr + ar);
        float zz = sigm((float)x01.y + cbz + az);
        float nn = tanhfast((float)x23.x + bin_ + rr * (an + bhn));
        hold = nn + zz * (hold - nn);

        if (q == 0) histf[s * HI_LD + j] = (_Float16)hold;
        __syncthreads();
      }
    }

    // ---- (d) fused FC over the chunk's hidden states ----
    if (wv < 2) {
      floatx4 facc = (floatx4){0.f, 0.f, 0.f, 0.f};
#pragma unroll
      for (int ks = 0; ks < 4; ++ks) {
        half8 af = *(const half8*)&histf[(wv * 16 + col) * HI_LD + ks * 32 + quad * 8];
        facc = __builtin_amdgcn_mfma_f32_16x16x32_f16(af, fcfrag[ks], facc, 0, 0, 0);
      }
      if (col < K_CLS) {
#pragma unroll
        for (int i = 0; i < 4; ++i) {
          int s  = wv * 16 + quad * 4 + i;
          int t  = ck * CHUNK + s;
          int tt = dir ? (T_LEN - 1 - t) : t;
          atomicAdd(out + ((size_t)b * T_LEN + tt) * K_CLS + col, facc[i]);
        }
      }
    }
  }
}

extern "C" void kernel_launch(void* const* d_in, const int* in_sizes, int n_in,
                              void* d_out, int out_size, void* d_ws, size_t ws_size,
                              hipStream_t stream) {
  (void)in_sizes; (void)n_in; (void)ws_size; (void)out_size;
  const float* x     = (const float*)d_in[0];
  const float* Wih_f = (const float*)d_in[1];
  const float* Whh_f = (const float*)d_in[2];
  const float* bih_f = (const float*)d_in[3];
  const float* bhh_f = (const float*)d_in[4];
  const float* Wih_b = (const float*)d_in[5];
  const float* Whh_b = (const float*)d_in[6];
  const float* bih_b = (const float*)d_in[7];
  const float* bhh_b = (const float*)d_in[8];
  const float* Wfc   = (const float*)d_in[9];
  const float* bfc   = (const float*)d_in[10];
  float* out = (float*)d_out;

  _Float16* w16 = (_Float16*)d_ws;   // [wih_f|wih_b]

  const int n_out = B_SZ * T_LEN * K_CLS;
  init_out_kernel<<<(n_out + 255) / 256, 256, 0, stream>>>(out, bfc);
  cvt_wih_kernel<<<(WMAT + 255) / 256, 256, 0, stream>>>(Wih_f, Wih_b, w16);
  gru_scan_kernel<<<B_SZ * 2, 256, 0, stream>>>(x, Whh_f, bih_f, bhh_f,
                                                Whh_b, bih_b, bhh_b,
                                                w16, Wfc, out);
}